// Round 8
// baseline (667.904 us; speedup 1.0000x reference)
//
#include <hip/hip_runtime.h>
#include <hip/hip_fp16.h>
#include <cstdint>
#include <cstddef>

// Problem constants (match reference)
static constexpr int cNA = 100000, cNP = 200000, cNU = 5000;
static constexpr int cDA = 128, cDP = 128, cDU = 64, cH = 32;
static constexpr int cEW = 2000000, cEP = 200000;

// ---------------------------------------------------------------------------
// prep: build combined per-node-type weight matrices and bias vectors.
//  W_A [128][33] : cols 0..31 = wr_Ws, col 32 = rw_Wd @ rw_ad
//  W_P [128][66] : cols 0..31 = pi_Ws, 32..63 = rw_Ws, 64 = wr_Wd@wr_ad, 65 = rp_Wd@rp_ad
//  W_U [ 64][33] : cols 0..31 = rp_Ws, col 32 = pi_Wd @ pi_ad
//  bias[0..31]=rw_b, bias[32..63]=0.5*(wr_b+rp_b), bias[64..95]=pi_b
// ---------------------------------------------------------------------------
__global__ void prep_kernel(
    const float* __restrict__ wr_Ws, const float* __restrict__ wr_Wd,
    const float* __restrict__ wr_ad, const float* __restrict__ wr_b,
    const float* __restrict__ pi_Ws, const float* __restrict__ pi_Wd,
    const float* __restrict__ pi_ad, const float* __restrict__ pi_b,
    const float* __restrict__ rw_Ws, const float* __restrict__ rw_Wd,
    const float* __restrict__ rw_ad, const float* __restrict__ rw_b,
    const float* __restrict__ rp_Ws, const float* __restrict__ rp_Wd,
    const float* __restrict__ rp_ad, const float* __restrict__ rp_b,
    float* __restrict__ W_A, float* __restrict__ W_P, float* __restrict__ W_U,
    float* __restrict__ bias)
{
    int k = threadIdx.x;  // 128 threads, 1 block
    if (k < 128) {
        for (int c = 0; c < 32; ++c) W_A[k * 33 + c] = wr_Ws[k * 32 + c];
        float dv = 0.f;
        for (int j = 0; j < 32; ++j) dv += rw_Wd[k * 32 + j] * rw_ad[j];
        W_A[k * 33 + 32] = dv;

        for (int c = 0; c < 32; ++c) W_P[k * 66 + c] = pi_Ws[k * 32 + c];
        for (int c = 0; c < 32; ++c) W_P[k * 66 + 32 + c] = rw_Ws[k * 32 + c];
        float d1 = 0.f, d2 = 0.f;
        for (int j = 0; j < 32; ++j) {
            d1 += wr_Wd[k * 32 + j] * wr_ad[j];
            d2 += rp_Wd[k * 32 + j] * rp_ad[j];
        }
        W_P[k * 66 + 64] = d1;
        W_P[k * 66 + 65] = d2;
    }
    if (k < 64) {
        for (int c = 0; c < 32; ++c) W_U[k * 33 + c] = rp_Ws[k * 32 + c];
        float dv = 0.f;
        for (int j = 0; j < 32; ++j) dv += pi_Wd[k * 32 + j] * pi_ad[j];
        W_U[k * 33 + 32] = dv;
    }
    if (k < 32) {
        bias[k]      = rw_b[k];
        bias[32 + k] = 0.5f * (wr_b[k] + rp_b[k]);
        bias[64 + k] = pi_b[k];
    }
}

// ---------------------------------------------------------------------------
// proj: per node type, one pass over x computing hs blocks (+ their s scalars)
// and d scalar columns. hs is stored PACKED AS HALF2 (32 ch -> 64B row = ONE
// cache line per edge gather). s/d stay fp32 (softmax inputs).
// ---------------------------------------------------------------------------
template <int D, int NHS, int ND>
__global__ __launch_bounds__(256) void proj_kernel(
    const float* __restrict__ x, const float* __restrict__ W, int N,
    const float* __restrict__ as0, const float* __restrict__ as1,
    __half2* __restrict__ hs0, float* __restrict__ s0,
    __half2* __restrict__ hs1, float* __restrict__ s1,
    float* __restrict__ dd0, float* __restrict__ dd1)
{
    constexpr int C = NHS * 32 + ND;
    int n = blockIdx.x * blockDim.x + threadIdx.x;
    if (n >= N) return;
    float acc[C];
#pragma unroll
    for (int c = 0; c < C; ++c) acc[c] = 0.f;
    const float* xr = x + (size_t)n * D;
    for (int k = 0; k < D; k += 4) {
        float4 xv = *reinterpret_cast<const float4*>(xr + k);
        const float* w = W + (size_t)k * C;
#pragma unroll
        for (int c = 0; c < C; ++c) acc[c] += xv.x * w[c];
#pragma unroll
        for (int c = 0; c < C; ++c) acc[c] += xv.y * w[C + c];
#pragma unroll
        for (int c = 0; c < C; ++c) acc[c] += xv.z * w[2 * C + c];
#pragma unroll
        for (int c = 0; c < C; ++c) acc[c] += xv.w * w[3 * C + c];
    }
    {
        float sv = 0.f;
#pragma unroll
        for (int c = 0; c < 32; ++c) sv += acc[c] * as0[c];
        s0[n] = sv;
        __half2 h2[16];
#pragma unroll
        for (int i = 0; i < 16; ++i)
            h2[i] = __floats2half2_rn(acc[2 * i], acc[2 * i + 1]);
        float4* o = reinterpret_cast<float4*>(hs0 + (size_t)n * 16);
        const float4* src4 = reinterpret_cast<const float4*>(h2);
#pragma unroll
        for (int i = 0; i < 4; ++i) o[i] = src4[i];
    }
    if constexpr (NHS == 2) {
        float sv = 0.f;
#pragma unroll
        for (int c = 0; c < 32; ++c) sv += acc[32 + c] * as1[c];
        s1[n] = sv;
        __half2 h2[16];
#pragma unroll
        for (int i = 0; i < 16; ++i)
            h2[i] = __floats2half2_rn(acc[32 + 2 * i], acc[32 + 2 * i + 1]);
        float4* o = reinterpret_cast<float4*>(hs1 + (size_t)n * 16);
        const float4* src4 = reinterpret_cast<const float4*>(h2);
#pragma unroll
        for (int i = 0; i < 4; ++i) o[i] = src4[i];
    }
    dd0[n] = acc[NHS * 32];
    if constexpr (ND == 2) dd1[n] = acc[NHS * 32 + 1];
}

// ---------------------------------------------------------------------------
// edge_sliced: both directions of the writes relation, DESTINATION-sliced so
// the acc/den atomic targets are XCD-L2-private.
// Default block->XCD mapping is round-robin (blockIdx % 8). Block with
// slice k processes:
//   fwd (author->paper): edges with (dst & 7) == k -> accF/denF rows private
//       (1.6 MB + 0.1 MB slice, L2-resident -> atomics are local L2 RMW hits,
//        no per-edge fabric write-through)
//   rev (paper->author): edges with (src & 7) == k -> accR/denR rows private
//       (0.8 MB + 0.05 MB slice)
// The two polluting read streams use NON-TEMPORAL loads so they don't evict
// the resident acc slice: the 8x-re-read edge list (L3-served, sequential)
// and the random hs row gathers (one 64B line each, deliberately uncached).
// Correctness does NOT depend on the mapping; it is a locality heuristic.
// Fill phase: 256 threads filter + compute ex, compact into LDS queues
// (max 256 entries/step by construction — no overflow). Drain phase:
// 16-lane groups per queue entry: nt hs gather + packed-half2 acc atomic +
// fp32 den atomic.
// ---------------------------------------------------------------------------
__global__ __launch_bounds__(256) void edge_sliced_kernel(
    const int* __restrict__ src, const int* __restrict__ dst,
    const float* __restrict__ sF, const float* __restrict__ dF,
    const float* __restrict__ sR, const float* __restrict__ dR,
    const __half2* __restrict__ hsF, const __half2* __restrict__ hsR,
    __half2* __restrict__ accF, float* __restrict__ denF,
    __half2* __restrict__ accR, float* __restrict__ denR,
    int E, int nblk)
{
    __shared__ int qsi[2][256];
    __shared__ int qdi[2][256];
    __shared__ float qex[2][256];
    __shared__ int qcnt[2];

    int slice = blockIdx.x & 7;
    int chunk = blockIdx.x >> 3;
    int per = (E + nblk - 1) / nblk;
    int e0 = chunk * per;
    int e1 = e0 + per;
    if (e1 > E) e1 = E;
    int t = threadIdx.x;
    if (t < 2) qcnt[t] = 0;
    __syncthreads();

    const uint32_t* hsFu = reinterpret_cast<const uint32_t*>(hsF);
    const uint32_t* hsRu = reinterpret_cast<const uint32_t*>(hsR);

    for (int base = e0; base < e1; base += 256) {
        // ---- fill: filter on DST side + compute ex, compact to queues ----
        int i = base + t;
        if (i < e1) {
            int si = __builtin_nontemporal_load(src + i);
            int di = __builtin_nontemporal_load(dst + i);
            if ((di & 7) == slice) {         // fwd: dst = paper
                float ev = sF[si] + dF[di];
                ev = ev >= 0.f ? ev : 0.2f * ev;
                float ex = __expf(ev);
                int p = atomicAdd(&qcnt[0], 1);
                qsi[0][p] = si; qdi[0][p] = di; qex[0][p] = ex;
            }
            if ((si & 7) == slice) {         // rev: dst = author
                float ev = sR[di] + dR[si];
                ev = ev >= 0.f ? ev : 0.2f * ev;
                float ex = __expf(ev);
                int p = atomicAdd(&qcnt[1], 1);
                qsi[1][p] = di; qdi[1][p] = si; qex[1][p] = ex;
            }
        }
        __syncthreads();
        // ---- drain: 16 groups x 16 lanes ----
        int nF = qcnt[0], nR = qcnt[1];
        int grp = t >> 4, l = t & 15;
        for (int q = grp; q < nF; q += 16) {
            int s_ = qsi[0][q], d_ = qdi[0][q];
            float ex = qex[0][q];
            uint32_t hraw = __builtin_nontemporal_load(hsFu + (size_t)s_ * 16 + l);
            float2 hf = __half22float2(*reinterpret_cast<__half2*>(&hraw));
            unsafeAtomicAdd(accF + (size_t)d_ * 16 + l,
                            __floats2half2_rn(ex * hf.x, ex * hf.y));
            if (l == 0) atomicAdd(denF + d_, ex);
        }
        for (int q = grp; q < nR; q += 16) {
            int s_ = qsi[1][q], d_ = qdi[1][q];
            float ex = qex[1][q];
            uint32_t hraw = __builtin_nontemporal_load(hsRu + (size_t)s_ * 16 + l);
            float2 hf = __half22float2(*reinterpret_cast<__half2*>(&hraw));
            unsafeAtomicAdd(accR + (size_t)d_ * 16 + l,
                            __floats2half2_rn(ex * hf.x, ex * hf.y));
            if (l == 0) atomicAdd(denR + d_, ex);
        }
        __syncthreads();
        if (t < 2) qcnt[t] = 0;
        __syncthreads();
    }
}

// ---------------------------------------------------------------------------
// edge: plain atomic path, kept for the small pub relations (200K edges).
// 16 lanes per edge; packed-half2 acc atomic; fp32 den atomic.
// ---------------------------------------------------------------------------
__global__ __launch_bounds__(256) void edge_kernel(
    const int* __restrict__ src, const int* __restrict__ dst,
    const float* __restrict__ s, const float* __restrict__ d,
    const __half2* __restrict__ hs, float* __restrict__ den,
    __half2* __restrict__ acc, int E)
{
    int g = blockIdx.x * 256 + threadIdx.x;
    int e = g >> 4;
    if (e >= E) return;
    int l = g & 15;
    int si = src[e], di = dst[e];
    float ev = s[si] + d[di];
    ev = ev >= 0.f ? ev : 0.2f * ev;
    float ex = __expf(ev);
    float2 hf = __half22float2(hs[(size_t)si * 16 + l]);
    __half2 contrib = __floats2half2_rn(ex * hf.x, ex * hf.y);
    unsafeAtomicAdd(acc + (size_t)di * 16 + l, contrib);
    if (l == 0) atomicAdd(den + di, ex);
}

// ---------------------------------------------------------------------------
// final: combine relations (half2 accs), /den (0 if no in-edges), +bias,
// relu, @lin_W + lin_b
// ---------------------------------------------------------------------------
__global__ __launch_bounds__(256) void final_kernel(
    const __half2* __restrict__ acc0, const float* __restrict__ den0,
    const __half2* __restrict__ acc1, const float* __restrict__ den1,
    const float* __restrict__ bias, float scale,
    const float* __restrict__ linW, const float* __restrict__ linb,
    float* __restrict__ out, int N)
{
    int n = blockIdx.x * blockDim.x + threadIdx.x;
    if (n >= N) return;
    float v[32];
    {
        float dn = den0[n];
        float inv = dn > 0.f ? 1.f / dn : 0.f;
        float4 t[4];
        const float4* a4 = reinterpret_cast<const float4*>(acc0 + (size_t)n * 16);
#pragma unroll
        for (int i = 0; i < 4; ++i) t[i] = a4[i];
        const __half2* hp = reinterpret_cast<const __half2*>(t);
#pragma unroll
        for (int k = 0; k < 16; ++k) {
            float2 f = __half22float2(hp[k]);
            v[2 * k] = f.x * inv;
            v[2 * k + 1] = f.y * inv;
        }
    }
    if (acc1 != nullptr) {
        float dn = den1[n];
        float inv = dn > 0.f ? 1.f / dn : 0.f;
        float4 t[4];
        const float4* a4 = reinterpret_cast<const float4*>(acc1 + (size_t)n * 16);
#pragma unroll
        for (int i = 0; i < 4; ++i) t[i] = a4[i];
        const __half2* hp = reinterpret_cast<const __half2*>(t);
#pragma unroll
        for (int k = 0; k < 16; ++k) {
            float2 f = __half22float2(hp[k]);
            v[2 * k] += f.x * inv;
            v[2 * k + 1] += f.y * inv;
        }
    }
#pragma unroll
    for (int h = 0; h < 32; ++h) {
        float t = scale * v[h] + bias[h];
        v[h] = t > 0.f ? t : 0.f;
    }
    float y[32];
#pragma unroll
    for (int j = 0; j < 32; ++j) y[j] = linb[j];
#pragma unroll
    for (int h = 0; h < 32; ++h) {
        float vh = v[h];
#pragma unroll
        for (int j = 0; j < 32; ++j) y[j] += vh * linW[h * 32 + j];
    }
    float4* o = reinterpret_cast<float4*>(out + (size_t)n * 32);
#pragma unroll
    for (int i = 0; i < 8; ++i)
        o[i] = make_float4(y[4 * i], y[4 * i + 1], y[4 * i + 2], y[4 * i + 3]);
}

extern "C" void kernel_launch(void* const* d_in, const int* in_sizes, int n_in,
                              void* d_out, int out_size, void* d_ws, size_t ws_size,
                              hipStream_t stream)
{
    const float* x_author = (const float*)d_in[0];
    const float* x_paper  = (const float*)d_in[1];
    const float* x_unit   = (const float*)d_in[2];
    const int* writes_src = (const int*)d_in[3];
    const int* writes_dst = (const int*)d_in[4];
    const int* pub_src    = (const int*)d_in[5];
    const int* pub_dst    = (const int*)d_in[6];
    const float* wr_Ws = (const float*)d_in[7];
    const float* wr_Wd = (const float*)d_in[8];
    const float* wr_as = (const float*)d_in[9];
    const float* wr_ad = (const float*)d_in[10];
    const float* wr_b  = (const float*)d_in[11];
    const float* pi_Ws = (const float*)d_in[12];
    const float* pi_Wd = (const float*)d_in[13];
    const float* pi_as = (const float*)d_in[14];
    const float* pi_ad = (const float*)d_in[15];
    const float* pi_b  = (const float*)d_in[16];
    const float* rw_Ws = (const float*)d_in[17];
    const float* rw_Wd = (const float*)d_in[18];
    const float* rw_as = (const float*)d_in[19];
    const float* rw_ad = (const float*)d_in[20];
    const float* rw_b  = (const float*)d_in[21];
    const float* rp_Ws = (const float*)d_in[22];
    const float* rp_Wd = (const float*)d_in[23];
    const float* rp_as = (const float*)d_in[24];
    const float* rp_ad = (const float*)d_in[25];
    const float* rp_b  = (const float*)d_in[26];
    const float* lin_W = (const float*)d_in[27];
    const float* lin_b = (const float*)d_in[28];
    float* out = (float*)d_out;
    float* ws = (float*)d_ws;

    // workspace layout (float offsets, padded to 64 floats = 256B)
    // hs/acc tables are __half2[16] per node = 16 float-equivalents per node.
    size_t off = 0;
    auto A = [&](size_t nf) { size_t o = off; off += (nf + 63) & ~(size_t)63; return o; };
    size_t oWA   = A(128 * 33);
    size_t oWP   = A(128 * 66);
    size_t oWU   = A(64 * 33);
    size_t oBias = A(96);
    size_t oHsWr = A((size_t)cNA * 16);
    size_t oHsPi = A((size_t)cNP * 16);
    size_t oHsRw = A((size_t)cNP * 16);
    size_t oHsRp = A((size_t)cNU * 16);
    size_t oSwr  = A(cNA);
    size_t oSpi  = A(cNP);
    size_t oSrw  = A(cNP);
    size_t oSrp  = A(cNU);
    size_t oDwr  = A(cNP);
    size_t oDrp  = A(cNP);
    size_t oDpi  = A(cNU);
    size_t oDrw  = A(cNA);
    // zero-region: dens (fp32) + accs (half2)
    size_t zs = off;
    size_t oDenWr = A(cNP);
    size_t oDenRw = A(cNA);
    size_t oDenPi = A(cNU);
    size_t oDenRp = A(cNP);
    size_t oAccWr = A((size_t)cNP * 16);
    size_t oAccRw = A((size_t)cNA * 16);
    size_t oAccPi = A((size_t)cNU * 16);
    size_t oAccRp = A((size_t)cNP * 16);
    size_t ze = off;

    hipMemsetAsync((void*)(ws + zs), 0, (ze - zs) * sizeof(float), stream);

    prep_kernel<<<1, 128, 0, stream>>>(
        wr_Ws, wr_Wd, wr_ad, wr_b,
        pi_Ws, pi_Wd, pi_ad, pi_b,
        rw_Ws, rw_Wd, rw_ad, rw_b,
        rp_Ws, rp_Wd, rp_ad, rp_b,
        ws + oWA, ws + oWP, ws + oWU, ws + oBias);

    proj_kernel<128, 1, 1><<<(cNA + 255) / 256, 256, 0, stream>>>(
        x_author, ws + oWA, cNA, wr_as, nullptr,
        (__half2*)(ws + oHsWr), ws + oSwr, nullptr, nullptr, ws + oDrw, nullptr);
    proj_kernel<128, 2, 2><<<(cNP + 255) / 256, 256, 0, stream>>>(
        x_paper, ws + oWP, cNP, pi_as, rw_as,
        (__half2*)(ws + oHsPi), ws + oSpi, (__half2*)(ws + oHsRw), ws + oSrw,
        ws + oDwr, ws + oDrp);
    proj_kernel<64, 1, 1><<<(cNU + 255) / 256, 256, 0, stream>>>(
        x_unit, ws + oWU, cNU, rp_as, nullptr,
        (__half2*)(ws + oHsRp), ws + oSrp, nullptr, nullptr, ws + oDpi, nullptr);

    // ---- writes relation: both directions, DST-XCD-slice-filtered ----
    {
        constexpr int nblk = 256;  // chunks; grid = 8 * nblk
        edge_sliced_kernel<<<8 * nblk, 256, 0, stream>>>(
            writes_src, writes_dst,
            ws + oSwr, ws + oDwr,          // fwd: s(author), d(paper)
            ws + oSrw, ws + oDrw,          // rev: s(paper),  d(author)
            (const __half2*)(ws + oHsWr), (const __half2*)(ws + oHsRw),
            (__half2*)(ws + oAccWr), ws + oDenWr,
            (__half2*)(ws + oAccRw), ws + oDenRw,
            cEW, nblk);
    }

    // ---- pub relations: plain atomic path (200K edges) ----
    {
        int blocks = (int)(((long long)cEP * 16 + 255) / 256);
        // pi: paper -> unit
        edge_kernel<<<blocks, 256, 0, stream>>>(
            pub_src, pub_dst, ws + oSpi, ws + oDpi,
            (const __half2*)(ws + oHsPi), ws + oDenPi,
            (__half2*)(ws + oAccPi), cEP);
        // rp: unit -> paper
        edge_kernel<<<blocks, 256, 0, stream>>>(
            pub_dst, pub_src, ws + oSrp, ws + oDrp,
            (const __half2*)(ws + oHsRp), ws + oDenRp,
            (__half2*)(ws + oAccRp), cEP);
    }

    // outputs: author, paper, unit (concatenated)
    final_kernel<<<(cNA + 255) / 256, 256, 0, stream>>>(
        (const __half2*)(ws + oAccRw), ws + oDenRw, nullptr, nullptr,
        ws + oBias + 0, 1.0f, lin_W, lin_b, out, cNA);
    final_kernel<<<(cNP + 255) / 256, 256, 0, stream>>>(
        (const __half2*)(ws + oAccWr), ws + oDenWr,
        (const __half2*)(ws + oAccRp), ws + oDenRp,
        ws + oBias + 32, 0.5f, lin_W, lin_b, out + (size_t)cNA * 32, cNP);
    final_kernel<<<(cNU + 255) / 256, 256, 0, stream>>>(
        (const __half2*)(ws + oAccPi), ws + oDenPi, nullptr, nullptr,
        ws + oBias + 64, 1.0f, lin_W, lin_b, out + (size_t)(cNA + cNP) * 32, cNU);
}

// Round 9
// 644.612 us; speedup vs baseline: 1.0361x; 1.0361x over previous
//
#include <hip/hip_runtime.h>
#include <hip/hip_fp16.h>
#include <cstdint>
#include <cstddef>

// Problem constants (match reference)
static constexpr int cNA = 100000, cNP = 200000, cNU = 5000;
static constexpr int cDA = 128, cDP = 128, cDU = 64, cH = 32;
static constexpr int cEW = 2000000, cEP = 200000;

// ---------------------------------------------------------------------------
// prep: build combined per-node-type weight matrices and bias vectors.
//  W_A [128][33] : cols 0..31 = wr_Ws, col 32 = rw_Wd @ rw_ad
//  W_P [128][66] : cols 0..31 = pi_Ws, 32..63 = rw_Ws, 64 = wr_Wd@wr_ad, 65 = rp_Wd@rp_ad
//  W_U [ 64][33] : cols 0..31 = rp_Ws, col 32 = pi_Wd @ pi_ad
//  bias[0..31]=rw_b, bias[32..63]=0.5*(wr_b+rp_b), bias[64..95]=pi_b
// ---------------------------------------------------------------------------
__global__ void prep_kernel(
    const float* __restrict__ wr_Ws, const float* __restrict__ wr_Wd,
    const float* __restrict__ wr_ad, const float* __restrict__ wr_b,
    const float* __restrict__ pi_Ws, const float* __restrict__ pi_Wd,
    const float* __restrict__ pi_ad, const float* __restrict__ pi_b,
    const float* __restrict__ rw_Ws, const float* __restrict__ rw_Wd,
    const float* __restrict__ rw_ad, const float* __restrict__ rw_b,
    const float* __restrict__ rp_Ws, const float* __restrict__ rp_Wd,
    const float* __restrict__ rp_ad, const float* __restrict__ rp_b,
    float* __restrict__ W_A, float* __restrict__ W_P, float* __restrict__ W_U,
    float* __restrict__ bias)
{
    int k = threadIdx.x;  // 128 threads, 1 block
    if (k < 128) {
        for (int c = 0; c < 32; ++c) W_A[k * 33 + c] = wr_Ws[k * 32 + c];
        float dv = 0.f;
        for (int j = 0; j < 32; ++j) dv += rw_Wd[k * 32 + j] * rw_ad[j];
        W_A[k * 33 + 32] = dv;

        for (int c = 0; c < 32; ++c) W_P[k * 66 + c] = pi_Ws[k * 32 + c];
        for (int c = 0; c < 32; ++c) W_P[k * 66 + 32 + c] = rw_Ws[k * 32 + c];
        float d1 = 0.f, d2 = 0.f;
        for (int j = 0; j < 32; ++j) {
            d1 += wr_Wd[k * 32 + j] * wr_ad[j];
            d2 += rp_Wd[k * 32 + j] * rp_ad[j];
        }
        W_P[k * 66 + 64] = d1;
        W_P[k * 66 + 65] = d2;
    }
    if (k < 64) {
        for (int c = 0; c < 32; ++c) W_U[k * 33 + c] = rp_Ws[k * 32 + c];
        float dv = 0.f;
        for (int j = 0; j < 32; ++j) dv += pi_Wd[k * 32 + j] * pi_ad[j];
        W_U[k * 33 + 32] = dv;
    }
    if (k < 32) {
        bias[k]      = rw_b[k];
        bias[32 + k] = 0.5f * (wr_b[k] + rp_b[k]);
        bias[64 + k] = pi_b[k];
    }
}

// ---------------------------------------------------------------------------
// proj: per node type, one pass over x computing hs blocks (+ their s scalars)
// and d scalar columns. hs is stored PACKED AS HALF2 (32 ch -> 64B row = ONE
// cache line per edge gather instead of two). s/d stay fp32 (softmax inputs).
// ---------------------------------------------------------------------------
template <int D, int NHS, int ND>
__global__ __launch_bounds__(256) void proj_kernel(
    const float* __restrict__ x, const float* __restrict__ W, int N,
    const float* __restrict__ as0, const float* __restrict__ as1,
    __half2* __restrict__ hs0, float* __restrict__ s0,
    __half2* __restrict__ hs1, float* __restrict__ s1,
    float* __restrict__ dd0, float* __restrict__ dd1)
{
    constexpr int C = NHS * 32 + ND;
    int n = blockIdx.x * blockDim.x + threadIdx.x;
    if (n >= N) return;
    float acc[C];
#pragma unroll
    for (int c = 0; c < C; ++c) acc[c] = 0.f;
    const float* xr = x + (size_t)n * D;
    for (int k = 0; k < D; k += 4) {
        float4 xv = *reinterpret_cast<const float4*>(xr + k);
        const float* w = W + (size_t)k * C;
#pragma unroll
        for (int c = 0; c < C; ++c) acc[c] += xv.x * w[c];
#pragma unroll
        for (int c = 0; c < C; ++c) acc[c] += xv.y * w[C + c];
#pragma unroll
        for (int c = 0; c < C; ++c) acc[c] += xv.z * w[2 * C + c];
#pragma unroll
        for (int c = 0; c < C; ++c) acc[c] += xv.w * w[3 * C + c];
    }
    {
        float sv = 0.f;
#pragma unroll
        for (int c = 0; c < 32; ++c) sv += acc[c] * as0[c];
        s0[n] = sv;
        __half2 h2[16];
#pragma unroll
        for (int i = 0; i < 16; ++i)
            h2[i] = __floats2half2_rn(acc[2 * i], acc[2 * i + 1]);
        float4* o = reinterpret_cast<float4*>(hs0 + (size_t)n * 16);
        const float4* src4 = reinterpret_cast<const float4*>(h2);
#pragma unroll
        for (int i = 0; i < 4; ++i) o[i] = src4[i];
    }
    if constexpr (NHS == 2) {
        float sv = 0.f;
#pragma unroll
        for (int c = 0; c < 32; ++c) sv += acc[32 + c] * as1[c];
        s1[n] = sv;
        __half2 h2[16];
#pragma unroll
        for (int i = 0; i < 16; ++i)
            h2[i] = __floats2half2_rn(acc[32 + 2 * i], acc[32 + 2 * i + 1]);
        float4* o = reinterpret_cast<float4*>(hs1 + (size_t)n * 16);
        const float4* src4 = reinterpret_cast<const float4*>(h2);
#pragma unroll
        for (int i = 0; i < 4; ++i) o[i] = src4[i];
    }
    dd0[n] = acc[NHS * 32];
    if constexpr (ND == 2) dd1[n] = acc[NHS * 32 + 1];
}

// ---------------------------------------------------------------------------
// edge: 16 lanes per edge (lane = half2 channel pair).
// ex = exp(leaky_relu(s[src]+d[dst])) computed in fp32;
// acc[dst] += ex*hs[src] via ONE packed-half2 atomic per lane (64B row = one
// line-visit instead of two); den[dst] += ex in fp32 (one 32B sector).
// Per edge: 3 random line-visits (hs fetch, acc RMW, den RMW) — the measured
// structural minimum; chip sustains ~30G visits/s on this pattern.
// Edge-index loads are non-temporal (one-touch streams) to keep the s/d
// scalar tables L2-resident.
// Softmax max-shift is skipped (|e| <= ~2 here, exp safe); normalization is
// deferred to final_kernel (acc/den), mathematically identical.
// ---------------------------------------------------------------------------
__global__ __launch_bounds__(256) void edge_kernel(
    const int* __restrict__ src, const int* __restrict__ dst,
    const float* __restrict__ s, const float* __restrict__ d,
    const __half2* __restrict__ hs, float* __restrict__ den,
    __half2* __restrict__ acc, int E)
{
    int g = blockIdx.x * 256 + threadIdx.x;
    int e = g >> 4;
    if (e >= E) return;
    int l = g & 15;
    int si = __builtin_nontemporal_load(src + e);
    int di = __builtin_nontemporal_load(dst + e);
    float ev = s[si] + d[di];
    ev = ev >= 0.f ? ev : 0.2f * ev;
    float ex = __expf(ev);
    float2 hf = __half22float2(hs[(size_t)si * 16 + l]);
    __half2 contrib = __floats2half2_rn(ex * hf.x, ex * hf.y);
    unsafeAtomicAdd(acc + (size_t)di * 16 + l, contrib);
    if (l == 0) atomicAdd(den + di, ex);
}

// ---------------------------------------------------------------------------
// final: combine relations (half2 accs), /den (0 if no in-edges), +bias,
// relu, @lin_W + lin_b
// ---------------------------------------------------------------------------
__global__ __launch_bounds__(256) void final_kernel(
    const __half2* __restrict__ acc0, const float* __restrict__ den0,
    const __half2* __restrict__ acc1, const float* __restrict__ den1,
    const float* __restrict__ bias, float scale,
    const float* __restrict__ linW, const float* __restrict__ linb,
    float* __restrict__ out, int N)
{
    int n = blockIdx.x * blockDim.x + threadIdx.x;
    if (n >= N) return;
    float v[32];
    {
        float dn = den0[n];
        float inv = dn > 0.f ? 1.f / dn : 0.f;
        float4 t[4];
        const float4* a4 = reinterpret_cast<const float4*>(acc0 + (size_t)n * 16);
#pragma unroll
        for (int i = 0; i < 4; ++i) t[i] = a4[i];
        const __half2* hp = reinterpret_cast<const __half2*>(t);
#pragma unroll
        for (int k = 0; k < 16; ++k) {
            float2 f = __half22float2(hp[k]);
            v[2 * k] = f.x * inv;
            v[2 * k + 1] = f.y * inv;
        }
    }
    if (acc1 != nullptr) {
        float dn = den1[n];
        float inv = dn > 0.f ? 1.f / dn : 0.f;
        float4 t[4];
        const float4* a4 = reinterpret_cast<const float4*>(acc1 + (size_t)n * 16);
#pragma unroll
        for (int i = 0; i < 4; ++i) t[i] = a4[i];
        const __half2* hp = reinterpret_cast<const __half2*>(t);
#pragma unroll
        for (int k = 0; k < 16; ++k) {
            float2 f = __half22float2(hp[k]);
            v[2 * k] += f.x * inv;
            v[2 * k + 1] += f.y * inv;
        }
    }
#pragma unroll
    for (int h = 0; h < 32; ++h) {
        float t = scale * v[h] + bias[h];
        v[h] = t > 0.f ? t : 0.f;
    }
    float y[32];
#pragma unroll
    for (int j = 0; j < 32; ++j) y[j] = linb[j];
#pragma unroll
    for (int h = 0; h < 32; ++h) {
        float vh = v[h];
#pragma unroll
        for (int j = 0; j < 32; ++j) y[j] += vh * linW[h * 32 + j];
    }
    float4* o = reinterpret_cast<float4*>(out + (size_t)n * 32);
#pragma unroll
    for (int i = 0; i < 8; ++i)
        o[i] = make_float4(y[4 * i], y[4 * i + 1], y[4 * i + 2], y[4 * i + 3]);
}

extern "C" void kernel_launch(void* const* d_in, const int* in_sizes, int n_in,
                              void* d_out, int out_size, void* d_ws, size_t ws_size,
                              hipStream_t stream)
{
    const float* x_author = (const float*)d_in[0];
    const float* x_paper  = (const float*)d_in[1];
    const float* x_unit   = (const float*)d_in[2];
    const int* writes_src = (const int*)d_in[3];
    const int* writes_dst = (const int*)d_in[4];
    const int* pub_src    = (const int*)d_in[5];
    const int* pub_dst    = (const int*)d_in[6];
    const float* wr_Ws = (const float*)d_in[7];
    const float* wr_Wd = (const float*)d_in[8];
    const float* wr_as = (const float*)d_in[9];
    const float* wr_ad = (const float*)d_in[10];
    const float* wr_b  = (const float*)d_in[11];
    const float* pi_Ws = (const float*)d_in[12];
    const float* pi_Wd = (const float*)d_in[13];
    const float* pi_as = (const float*)d_in[14];
    const float* pi_ad = (const float*)d_in[15];
    const float* pi_b  = (const float*)d_in[16];
    const float* rw_Ws = (const float*)d_in[17];
    const float* rw_Wd = (const float*)d_in[18];
    const float* rw_as = (const float*)d_in[19];
    const float* rw_ad = (const float*)d_in[20];
    const float* rw_b  = (const float*)d_in[21];
    const float* rp_Ws = (const float*)d_in[22];
    const float* rp_Wd = (const float*)d_in[23];
    const float* rp_as = (const float*)d_in[24];
    const float* rp_ad = (const float*)d_in[25];
    const float* rp_b  = (const float*)d_in[26];
    const float* lin_W = (const float*)d_in[27];
    const float* lin_b = (const float*)d_in[28];
    float* out = (float*)d_out;
    float* ws = (float*)d_ws;

    // workspace layout (float offsets, padded to 64 floats = 256B)
    // hs/acc tables are __half2[16] per node = 16 float-equivalents per node.
    size_t off = 0;
    auto A = [&](size_t nf) { size_t o = off; off += (nf + 63) & ~(size_t)63; return o; };
    size_t oWA   = A(128 * 33);
    size_t oWP   = A(128 * 66);
    size_t oWU   = A(64 * 33);
    size_t oBias = A(96);
    size_t oHsWr = A((size_t)cNA * 16);
    size_t oHsPi = A((size_t)cNP * 16);
    size_t oHsRw = A((size_t)cNP * 16);
    size_t oHsRp = A((size_t)cNU * 16);
    size_t oSwr  = A(cNA);
    size_t oSpi  = A(cNP);
    size_t oSrw  = A(cNP);
    size_t oSrp  = A(cNU);
    size_t oDwr  = A(cNP);
    size_t oDrp  = A(cNP);
    size_t oDpi  = A(cNU);
    size_t oDrw  = A(cNA);
    // zero-region: dens (fp32) + accs (half2)
    size_t zs = off;
    size_t oDenWr = A(cNP);
    size_t oDenRw = A(cNA);
    size_t oDenPi = A(cNU);
    size_t oDenRp = A(cNP);
    size_t oAccWr = A((size_t)cNP * 16);
    size_t oAccRw = A((size_t)cNA * 16);
    size_t oAccPi = A((size_t)cNU * 16);
    size_t oAccRp = A((size_t)cNP * 16);
    size_t ze = off;

    hipMemsetAsync((void*)(ws + zs), 0, (ze - zs) * sizeof(float), stream);

    prep_kernel<<<1, 128, 0, stream>>>(
        wr_Ws, wr_Wd, wr_ad, wr_b,
        pi_Ws, pi_Wd, pi_ad, pi_b,
        rw_Ws, rw_Wd, rw_ad, rw_b,
        rp_Ws, rp_Wd, rp_ad, rp_b,
        ws + oWA, ws + oWP, ws + oWU, ws + oBias);

    proj_kernel<128, 1, 1><<<(cNA + 255) / 256, 256, 0, stream>>>(
        x_author, ws + oWA, cNA, wr_as, nullptr,
        (__half2*)(ws + oHsWr), ws + oSwr, nullptr, nullptr, ws + oDrw, nullptr);
    proj_kernel<128, 2, 2><<<(cNP + 255) / 256, 256, 0, stream>>>(
        x_paper, ws + oWP, cNP, pi_as, rw_as,
        (__half2*)(ws + oHsPi), ws + oSpi, (__half2*)(ws + oHsRw), ws + oSrw,
        ws + oDwr, ws + oDrp);
    proj_kernel<64, 1, 1><<<(cNU + 255) / 256, 256, 0, stream>>>(
        x_unit, ws + oWU, cNU, rp_as, nullptr,
        (__half2*)(ws + oHsRp), ws + oSrp, nullptr, nullptr, ws + oDpi, nullptr);

    // relation edge passes (16 lanes per edge)
    {
        int blocks = (int)(((long long)cEW * 16 + 255) / 256);
        // wr: author -> paper
        edge_kernel<<<blocks, 256, 0, stream>>>(
            writes_src, writes_dst, ws + oSwr, ws + oDwr,
            (const __half2*)(ws + oHsWr), ws + oDenWr,
            (__half2*)(ws + oAccWr), cEW);
        // rw: paper -> author
        edge_kernel<<<blocks, 256, 0, stream>>>(
            writes_dst, writes_src, ws + oSrw, ws + oDrw,
            (const __half2*)(ws + oHsRw), ws + oDenRw,
            (__half2*)(ws + oAccRw), cEW);
    }
    {
        int blocks = (int)(((long long)cEP * 16 + 255) / 256);
        // pi: paper -> unit
        edge_kernel<<<blocks, 256, 0, stream>>>(
            pub_src, pub_dst, ws + oSpi, ws + oDpi,
            (const __half2*)(ws + oHsPi), ws + oDenPi,
            (__half2*)(ws + oAccPi), cEP);
        // rp: unit -> paper
        edge_kernel<<<blocks, 256, 0, stream>>>(
            pub_dst, pub_src, ws + oSrp, ws + oDrp,
            (const __half2*)(ws + oHsRp), ws + oDenRp,
            (__half2*)(ws + oAccRp), cEP);
    }

    // outputs: author, paper, unit (concatenated)
    final_kernel<<<(cNA + 255) / 256, 256, 0, stream>>>(
        (const __half2*)(ws + oAccRw), ws + oDenRw, nullptr, nullptr,
        ws + oBias + 0, 1.0f, lin_W, lin_b, out, cNA);
    final_kernel<<<(cNP + 255) / 256, 256, 0, stream>>>(
        (const __half2*)(ws + oAccWr), ws + oDenWr,
        (const __half2*)(ws + oAccRp), ws + oDenRp,
        ws + oBias + 32, 0.5f, lin_W, lin_b, out + (size_t)cNA * 32, cNP);
    final_kernel<<<(cNU + 255) / 256, 256, 0, stream>>>(
        (const __half2*)(ws + oAccPi), ws + oDenPi, nullptr, nullptr,
        ws + oBias + 64, 1.0f, lin_W, lin_b, out + (size_t)(cNA + cNP) * 32, cNU);
}